// Round 2
// baseline (7888.229 us; speedup 1.0000x reference)
//
#include <hip/hip_runtime.h>
#include <cstddef>

#define DEVFN __device__ __forceinline__

DEVFN float sigmoidf_(float x) { return 1.0f / (1.0f + __expf(-x)); }
DEVFN float tanh_fast(float x) {
    float e = __expf(2.0f * x);
    return 1.0f - 2.0f / (e + 1.0f);
}

// ---------------------------------------------------------------------------
// Conv stem: x (16,1,128,1024), w (32,1,3,3), stride 2, pad 1 -> (16,32,64,512)
// ---------------------------------------------------------------------------
__global__ __launch_bounds__(256)
void conv_stem(const float* __restrict__ x, const float* __restrict__ w,
               const float* __restrict__ cb, float* __restrict__ out)
{
    const int b = blockIdx.z;
    const int h = blockIdx.y * 4 + (threadIdx.x >> 6);
    const int wc = blockIdx.x * 64 + (threadIdx.x & 63);
    float iv[9];
#pragma unroll
    for (int kh = 0; kh < 3; ++kh)
#pragma unroll
        for (int kw = 0; kw < 3; ++kw) {
            int ih = 2 * h - 1 + kh, iw = 2 * wc - 1 + kw;
            iv[kh * 3 + kw] = (ih >= 0 && ih < 128 && iw >= 0 && iw < 1024)
                ? x[(size_t)b * 131072 + (size_t)ih * 1024 + iw] : 0.0f;
        }
#pragma unroll
    for (int co = 0; co < 32; ++co) {
        const float* wp = w + co * 9;   // wave-uniform -> s_load
        float a = cb[co];
#pragma unroll
        for (int q = 0; q < 9; ++q) a = fmaf(iv[q], wp[q], a);
        out[(((size_t)b * 32 + co) * 64 + h) * 512 + wc] = a;
    }
}

// ---------------------------------------------------------------------------
// Residual-block conv: 3x3, 32->32, pad 1 + BN (+residual) + ReLU, fused.
// Block: 256 threads, tile = 4 rows x 64 cols, all 32 c_out per thread.
// LDS: input patch 32ci x 6r x 66c = 49.5 KB (3 blocks/CU).
// Weights read with wave-uniform indices -> scalar loads.
// ---------------------------------------------------------------------------
template <bool RES>
__global__ __launch_bounds__(256)
void conv3x3_bn(const float* __restrict__ in, const float* __restrict__ wgt,
                const float* __restrict__ cb,
                const float* __restrict__ g, const float* __restrict__ bb,
                const float* __restrict__ m, const float* __restrict__ vv,
                const float* __restrict__ res, float* __restrict__ out)
{
    __shared__ float sp[32][6][66];
    const int b = blockIdx.z;
    const int h0 = blockIdx.y * 4;
    const int w0 = blockIdx.x * 64;
    for (int i = threadIdx.x; i < 32 * 6 * 66; i += 256) {
        int ci = i / 396; int rem = i - ci * 396;
        int r = rem / 66; int cc = rem - r * 66;
        int gh = h0 + r - 1, gw = w0 + cc - 1;
        float v = 0.0f;
        if (gh >= 0 && gh < 64 && gw >= 0 && gw < 512)
            v = in[(((size_t)b * 32 + ci) * 64 + gh) * 512 + gw];
        sp[ci][r][cc] = v;
    }
    __syncthreads();
    const int ph = threadIdx.x >> 6, pw = threadIdx.x & 63;
    float acc[32];
#pragma unroll
    for (int co = 0; co < 32; ++co) acc[co] = 0.0f;
    for (int ci = 0; ci < 32; ++ci) {
        float iv[9];
#pragma unroll
        for (int kh = 0; kh < 3; ++kh)
#pragma unroll
            for (int kw = 0; kw < 3; ++kw)
                iv[kh * 3 + kw] = sp[ci][ph + kh][pw + kw];
#pragma unroll
        for (int co = 0; co < 32; ++co) {
            const float* wp = wgt + (co * 32 + ci) * 9;  // uniform -> s_load
            float a = acc[co];
#pragma unroll
            for (int q = 0; q < 9; ++q) a = fmaf(iv[q], wp[q], a);
            acc[co] = a;
        }
    }
    const int h = h0 + ph, wc = w0 + pw;
#pragma unroll
    for (int co = 0; co < 32; ++co) {
        float scale = g[co] * rsqrtf(vv[co] + 1e-5f);
        float shift = bb[co] - m[co] * scale + cb[co] * scale;
        float v = acc[co] * scale + shift;
        size_t idx = (((size_t)b * 32 + co) * 64 + h) * 512 + wc;
        if (RES) v += res[idx];
        out[idx] = fmaxf(v, 0.0f);
    }
}

// ---------------------------------------------------------------------------
// Gather/transpose: y (16, 2048, 512) [b, j=c*64+h, t] -> xrow[(t*16+b)][j]
// ---------------------------------------------------------------------------
__global__ __launch_bounds__(256)
void gather_xrow(const float* __restrict__ y, float* __restrict__ xrow)
{
    __shared__ float tile[64][65];
    const int b = blockIdx.z;
    const int j0 = blockIdx.y * 64;
    const int t0 = blockIdx.x * 64;
#pragma unroll
    for (int p = 0; p < 16; ++p) {
        int idx = p * 256 + threadIdx.x;
        int jl = idx >> 6, tl = idx & 63;
        tile[jl][tl] = y[((size_t)b * 2048 + j0 + jl) * 512 + t0 + tl];
    }
    __syncthreads();
#pragma unroll
    for (int p = 0; p < 16; ++p) {
        int idx = p * 256 + threadIdx.x;
        int tl = idx >> 6, jl = idx & 63;
        xrow[((size_t)(t0 + tl) * 16 + b) * 2048 + j0 + jl] = tile[jl][tl];
    }
}

// ---------------------------------------------------------------------------
// LayerNorm over last dim (1024), rows = 8192. Biased variance, eps 1e-5.
// ---------------------------------------------------------------------------
__global__ __launch_bounds__(256)
void layernorm1024(const float* __restrict__ x, const float* __restrict__ g,
                   const float* __restrict__ b, float* __restrict__ y)
{
    const size_t row = blockIdx.x;
    const float4 v = ((const float4*)(x + row * 1024))[threadIdx.x];
    float s = v.x + v.y + v.z + v.w;
    float s2 = v.x * v.x + v.y * v.y + v.z * v.z + v.w * v.w;
#pragma unroll
    for (int off = 32; off; off >>= 1) {
        s += __shfl_down(s, off);
        s2 += __shfl_down(s2, off);
    }
    __shared__ float red[2][4];
    int wid = threadIdx.x >> 6, lane = threadIdx.x & 63;
    if (lane == 0) { red[0][wid] = s; red[1][wid] = s2; }
    __syncthreads();
    s = red[0][0] + red[0][1] + red[0][2] + red[0][3];
    s2 = red[1][0] + red[1][1] + red[1][2] + red[1][3];
    float mu = s * (1.0f / 1024.0f);
    float var = s2 * (1.0f / 1024.0f) - mu * mu;
    float rstd = rsqrtf(var + 1e-5f);
    float4 gv = ((const float4*)g)[threadIdx.x];
    float4 bv = ((const float4*)b)[threadIdx.x];
    float4 o;
    o.x = (v.x - mu) * rstd * gv.x + bv.x;
    o.y = (v.y - mu) * rstd * gv.y + bv.y;
    o.z = (v.z - mu) * rstd * gv.z + bv.z;
    o.w = (v.w - mu) * rstd * gv.w + bv.w;
    ((float4*)(y + row * 1024))[threadIdx.x] = o;
}

// ---------------------------------------------------------------------------
// fp32 GEMM: C[M,N] = A[M,K] @ B[K,N], optional ReLU.
// BM=BN=128, BK=8; 256 threads; 8x8 register tile per thread.
// ---------------------------------------------------------------------------
template <bool RELU>
__global__ __launch_bounds__(256)
void gemm_f32(const float* __restrict__ A, const float* __restrict__ B,
              float* __restrict__ C, int M, int N, int K)
{
    __shared__ float As[8][128];
    __shared__ float Bs[8][128];
    const int tid = threadIdx.x;
    const int m0 = blockIdx.y * 128, n0 = blockIdx.x * 128;
    const int ty = tid >> 4, tx = tid & 15;
    const int mb = ty * 8, nb = tx * 8;
    const int arow = tid >> 1, akq = (tid & 1) * 4;
    const int bk = tid >> 5, bn4 = (tid & 31) * 4;
    const float* Ap = A + (size_t)(m0 + arow) * K + akq;
    const float* Bp = B + (size_t)bk * N + n0 + bn4;
    float acc[8][8];
#pragma unroll
    for (int i = 0; i < 8; ++i)
#pragma unroll
        for (int j = 0; j < 8; ++j) acc[i][j] = 0.0f;

    for (int k0 = 0; k0 < K; k0 += 8) {
        float4 a4 = *reinterpret_cast<const float4*>(Ap + k0);
        float4 b4 = *reinterpret_cast<const float4*>(Bp + (size_t)k0 * N);
        __syncthreads();
        As[akq + 0][arow] = a4.x;
        As[akq + 1][arow] = a4.y;
        As[akq + 2][arow] = a4.z;
        As[akq + 3][arow] = a4.w;
        *reinterpret_cast<float4*>(&Bs[bk][bn4]) = b4;
        __syncthreads();
#pragma unroll
        for (int kk = 0; kk < 8; ++kk) {
            float4 a0 = *reinterpret_cast<const float4*>(&As[kk][mb]);
            float4 a1 = *reinterpret_cast<const float4*>(&As[kk][mb + 4]);
            float4 b0 = *reinterpret_cast<const float4*>(&Bs[kk][nb]);
            float4 b1 = *reinterpret_cast<const float4*>(&Bs[kk][nb + 4]);
            float av[8] = {a0.x, a0.y, a0.z, a0.w, a1.x, a1.y, a1.z, a1.w};
            float bv[8] = {b0.x, b0.y, b0.z, b0.w, b1.x, b1.y, b1.z, b1.w};
#pragma unroll
            for (int i = 0; i < 8; ++i)
#pragma unroll
                for (int j = 0; j < 8; ++j)
                    acc[i][j] = fmaf(av[i], bv[j], acc[i][j]);
        }
    }
#pragma unroll
    for (int i = 0; i < 8; ++i) {
        size_t row = (size_t)(m0 + mb + i) * N + n0 + nb;
#pragma unroll
        for (int j = 0; j < 8; j += 4) {
            float4 v;
            v.x = acc[i][j]; v.y = acc[i][j + 1];
            v.z = acc[i][j + 2]; v.w = acc[i][j + 3];
            if (RELU) {
                v.x = fmaxf(v.x, 0.0f); v.y = fmaxf(v.y, 0.0f);
                v.z = fmaxf(v.z, 0.0f); v.w = fmaxf(v.w, 0.0f);
            }
            *reinterpret_cast<float4*>(C + row + j) = v;
        }
    }
}

// ---------------------------------------------------------------------------
// SRU scan. U: (8192 rows = t*16+b, 2048 = [xt|fp|rp|xp]); v,bb: (2,512).
// One thread per (b, j) chain; dir folds the sequence reversal into
// iteration order (U is computed un-reversed).
// out rows (t*16+b), cols dir*512 + j, ld = 1024.
// ---------------------------------------------------------------------------
__global__ __launch_bounds__(256)
void sru_scan(const float* __restrict__ U, const float* __restrict__ v,
              const float* __restrict__ bb, float* __restrict__ out, int dir)
{
    const int gidx = blockIdx.x * 256 + threadIdx.x;   // 0..8191
    const int j = gidx & 511, b = gidx >> 9;
    const float vf = v[j], vr = v[512 + j];
    const float bf = bb[j], br = bb[512 + j];
    const int co = (dir ? 512 : 0) + j;
    float c = 0.0f;
    for (int ti = 0; ti < 512; ++ti) {
        const int t = dir ? (511 - ti) : ti;
        const float* row = U + ((size_t)t * 16 + b) * 2048;
        float xt = row[j], fp = row[512 + j], rp = row[1024 + j], xp = row[1536 + j];
        float f = sigmoidf_(fp + vf * c + bf);
        float r = sigmoidf_(rp + vr * c + br);
        c = fmaf(f, c - xt, xt);
        float h = fmaf(r, tanh_fast(c) - xp, xp);
        out[((size_t)t * 16 + b) * 1024 + co] = h;
    }
}

// ---------------------------------------------------------------------------
// Final small GEMM (8192,512)@(512,29) with (t,b)->(b,t) output scatter.
// ---------------------------------------------------------------------------
__global__ __launch_bounds__(256)
void cls_out(const float* __restrict__ h1, const float* __restrict__ W2,
             float* __restrict__ out)
{
    const int gidx = blockIdx.x * 256 + threadIdx.x;
    const int n = gidx & 31, m = gidx >> 5;  // m in [0,8192)
    if (n >= 29) return;
    const float* hr = h1 + (size_t)m * 512;
    float acc = 0.0f;
    for (int k = 0; k < 512; k += 4) {
        acc = fmaf(hr[k + 0], W2[(k + 0) * 29 + n], acc);
        acc = fmaf(hr[k + 1], W2[(k + 1) * 29 + n], acc);
        acc = fmaf(hr[k + 2], W2[(k + 2) * 29 + n], acc);
        acc = fmaf(hr[k + 3], W2[(k + 3) * 29 + n], acc);
    }
    const int t = m >> 4, b = m & 15;
    out[((size_t)b * 512 + t) * 29 + n] = acc;
}

// ---------------------------------------------------------------------------
// Host orchestration.
// Workspace layout (floats): B0 [0,16.78M) B1 [16.78M,33.55M) B2 [33.55M,50.33M)
// Peak use: 50,331,648 floats = 201.3 MB.
// ---------------------------------------------------------------------------
extern "C" void kernel_launch(void* const* d_in, const int* in_sizes, int n_in,
                              void* d_out, int out_size, void* d_ws, size_t ws_size,
                              hipStream_t stream)
{
    (void)in_sizes; (void)n_in; (void)out_size; (void)ws_size;
    const float* x      = (const float*)d_in[0];
    const float* cnn_w  = (const float*)d_in[1];
    const float* cnn_b  = (const float*)d_in[2];
    const float* c1w    = (const float*)d_in[3];
    const float* c1b    = (const float*)d_in[4];
    const float* bn1g   = (const float*)d_in[5];
    const float* bn1b   = (const float*)d_in[6];
    const float* bn1m   = (const float*)d_in[7];
    const float* bn1v   = (const float*)d_in[8];
    const float* c2w    = (const float*)d_in[9];
    const float* c2b    = (const float*)d_in[10];
    const float* bn2g   = (const float*)d_in[11];
    const float* bn2b   = (const float*)d_in[12];
    const float* bn2m   = (const float*)d_in[13];
    const float* bn2v   = (const float*)d_in[14];
    const float* projW  = (const float*)d_in[15];
    const float* sruW   = (const float*)d_in[16];
    const float* sruV   = (const float*)d_in[17];
    const float* sruB   = (const float*)d_in[18];
    const float* sruLNg = (const float*)d_in[19];
    const float* sruLNb = (const float*)d_in[20];
    const float* clsLNg = (const float*)d_in[21];
    const float* clsLNb = (const float*)d_in[22];
    const float* W1     = (const float*)d_in[23];
    const float* W2     = (const float*)d_in[24];
    float* out = (float*)d_out;
    float* ws  = (float*)d_ws;

    float* B0 = ws;
    float* B1 = ws + 16777216;
    float* B2 = ws + 33554432;

    dim3 blk(256);

    // Stem -> B0
    conv_stem<<<dim3(8, 16, 16), blk, 0, stream>>>(x, cnn_w, cnn_b, B0);

    // Residual blocks (buffer rotation; after 3 blocks y lands in B0)
    float* ybuf = B0; float* tbuf = B1; float* obuf = B2;
    for (int i = 0; i < 3; ++i) {
        conv3x3_bn<false><<<dim3(8, 16, 16), blk, 0, stream>>>(
            ybuf, c1w + i * 9216, c1b + i * 32, bn1g + i * 32, bn1b + i * 32,
            bn1m + i * 32, bn1v + i * 32, nullptr, tbuf);
        conv3x3_bn<true><<<dim3(8, 16, 16), blk, 0, stream>>>(
            tbuf, c2w + i * 9216, c2b + i * 32, bn2g + i * 32, bn2b + i * 32,
            bn2m + i * 32, bn2v + i * 32, ybuf, obuf);
        float* ny = obuf; obuf = tbuf; tbuf = ybuf; ybuf = ny;
    }
    // Now: ybuf = conv output, tbuf & obuf free.

    // Gather -> xrow (full tbuf region, 8192 x 2048)
    gather_xrow<<<dim3(8, 32, 16), blk, 0, stream>>>(ybuf, tbuf);

    float* Ubuf = ybuf;                 // 16.78M floats
    float* h1a = tbuf;                  // 8.39M
    float* h1b = tbuf + 8388608;
    float* h2a = obuf;
    float* h2b = obuf + 8388608;

    // proj: (8192,2048) @ (2048,1024) -> h2a
    gemm_f32<false><<<dim3(8, 64), blk, 0, stream>>>(tbuf, projW, h2a, 8192, 1024, 2048);

    // SRU layers
    float* xc = h2a; float* xnx = h1a;
    for (int l = 0; l < 4; ++l) {
        layernorm1024<<<8192, blk, 0, stream>>>(xc, sruLNg + l * 1024,
                                                sruLNb + l * 1024, h2b);
        for (int dir = 0; dir < 2; ++dir) {
            gemm_f32<false><<<dim3(16, 64), blk, 0, stream>>>(
                h2b, sruW + (size_t)(l * 2 + dir) * 2097152, Ubuf, 8192, 2048, 1024);
            sru_scan<<<32, blk, 0, stream>>>(
                Ubuf, sruV + (l * 2 + dir) * 1024, sruB + (l * 2 + dir) * 1024,
                xnx, dir);
        }
        float* tmp = xc; xc = xnx; xnx = tmp;
    }
    // xc = final SRU output (h2a), xnx = h1a free.

    // Classifier
    layernorm1024<<<8192, blk, 0, stream>>>(xc, clsLNg, clsLNb, xnx);
    gemm_f32<true><<<dim3(4, 64), blk, 0, stream>>>(xnx, W1, h1b, 8192, 512, 1024);
    cls_out<<<1024, blk, 0, stream>>>(h1b, W2, out);
}

// Round 3
// 3250.820 us; speedup vs baseline: 2.4265x; 2.4265x over previous
//
#include <hip/hip_runtime.h>
#include <cstddef>

#define DEVFN __device__ __forceinline__

typedef __attribute__((ext_vector_type(8))) short short8;   // 8 bf16 (4 VGPRs)
typedef __attribute__((ext_vector_type(4))) float f32x4;    // MFMA accumulator

DEVFN float sigmoidf_(float x) { return 1.0f / (1.0f + __expf(-x)); }
DEVFN float tanh_fast(float x) {
    float e = __expf(2.0f * x);
    return 1.0f - 2.0f / (e + 1.0f);
}
DEVFN unsigned short f2bf(float f) {            // round-to-nearest-even
    unsigned int u = __float_as_uint(f);
    return (unsigned short)((u + 0x7FFFu + ((u >> 16) & 1u)) >> 16);
}
DEVFN float b2f(unsigned int bits) { return __uint_as_float(bits << 16); }

DEVFN void gload_lds16(const ushort* g, ushort* l) {
    __builtin_amdgcn_global_load_lds(
        (const __attribute__((address_space(1))) unsigned int*)g,
        (__attribute__((address_space(3))) unsigned int*)l, 16, 0, 0);
}

// ---------------------------------------------------------------------------
// Conv stem: x (16,1,128,1024), w (32,1,3,3), stride 2, pad 1 -> (16,32,64,512)
// ---------------------------------------------------------------------------
__global__ __launch_bounds__(256)
void conv_stem(const float* __restrict__ x, const float* __restrict__ w,
               const float* __restrict__ cb, float* __restrict__ out)
{
    const int b = blockIdx.z;
    const int h = blockIdx.y * 4 + (threadIdx.x >> 6);
    const int wc = blockIdx.x * 64 + (threadIdx.x & 63);
    float iv[9];
#pragma unroll
    for (int kh = 0; kh < 3; ++kh)
#pragma unroll
        for (int kw = 0; kw < 3; ++kw) {
            int ih = 2 * h - 1 + kh, iw = 2 * wc - 1 + kw;
            iv[kh * 3 + kw] = (ih >= 0 && ih < 128 && iw >= 0 && iw < 1024)
                ? x[(size_t)b * 131072 + (size_t)ih * 1024 + iw] : 0.0f;
        }
#pragma unroll
    for (int co = 0; co < 32; ++co) {
        const float* wp = w + co * 9;   // wave-uniform -> s_load
        float a = cb[co];
#pragma unroll
        for (int q = 0; q < 9; ++q) a = fmaf(iv[q], wp[q], a);
        out[(((size_t)b * 32 + co) * 64 + h) * 512 + wc] = a;
    }
}

// ---------------------------------------------------------------------------
// Residual-block conv 3x3 + BN (+res) + ReLU (unchanged from round 1)
// ---------------------------------------------------------------------------
template <bool RES>
__global__ __launch_bounds__(256)
void conv3x3_bn(const float* __restrict__ in, const float* __restrict__ wgt,
                const float* __restrict__ cb,
                const float* __restrict__ g, const float* __restrict__ bb,
                const float* __restrict__ m, const float* __restrict__ vv,
                const float* __restrict__ res, float* __restrict__ out)
{
    __shared__ float sp[32][6][66];
    const int b = blockIdx.z;
    const int h0 = blockIdx.y * 4;
    const int w0 = blockIdx.x * 64;
    for (int i = threadIdx.x; i < 32 * 6 * 66; i += 256) {
        int ci = i / 396; int rem = i - ci * 396;
        int r = rem / 66; int cc = rem - r * 66;
        int gh = h0 + r - 1, gw = w0 + cc - 1;
        float v = 0.0f;
        if (gh >= 0 && gh < 64 && gw >= 0 && gw < 512)
            v = in[(((size_t)b * 32 + ci) * 64 + gh) * 512 + gw];
        sp[ci][r][cc] = v;
    }
    __syncthreads();
    const int ph = threadIdx.x >> 6, pw = threadIdx.x & 63;
    float acc[32];
#pragma unroll
    for (int co = 0; co < 32; ++co) acc[co] = 0.0f;
    for (int ci = 0; ci < 32; ++ci) {
        float iv[9];
#pragma unroll
        for (int kh = 0; kh < 3; ++kh)
#pragma unroll
            for (int kw = 0; kw < 3; ++kw)
                iv[kh * 3 + kw] = sp[ci][ph + kh][pw + kw];
#pragma unroll
        for (int co = 0; co < 32; ++co) {
            const float* wp = wgt + (co * 32 + ci) * 9;  // uniform -> s_load
            float a = acc[co];
#pragma unroll
            for (int q = 0; q < 9; ++q) a = fmaf(iv[q], wp[q], a);
            acc[co] = a;
        }
    }
    const int h = h0 + ph, wc = w0 + pw;
#pragma unroll
    for (int co = 0; co < 32; ++co) {
        float scale = g[co] * rsqrtf(vv[co] + 1e-5f);
        float shift = bb[co] - m[co] * scale + cb[co] * scale;
        float v = acc[co] * scale + shift;
        size_t idx = (((size_t)b * 32 + co) * 64 + h) * 512 + wc;
        if (RES) v += res[idx];
        out[idx] = fmaxf(v, 0.0f);
    }
}

// ---------------------------------------------------------------------------
// Gather/transpose: y (16,2048,512) [b, j, t] -> xrow_bf16[(t*16+b)][j]
// ---------------------------------------------------------------------------
__global__ __launch_bounds__(256)
void gather_xrow(const float* __restrict__ y, ushort* __restrict__ xrow)
{
    __shared__ float tile[64][65];
    const int b = blockIdx.z;
    const int j0 = blockIdx.y * 64;
    const int t0 = blockIdx.x * 64;
#pragma unroll
    for (int p = 0; p < 16; ++p) {
        int idx = p * 256 + threadIdx.x;
        int jl = idx >> 6, tl = idx & 63;
        tile[jl][tl] = y[((size_t)b * 2048 + j0 + jl) * 512 + t0 + tl];
    }
    __syncthreads();
#pragma unroll
    for (int p = 0; p < 16; ++p) {
        int idx = p * 256 + threadIdx.x;
        int tl = idx >> 6, jl = idx & 63;
        xrow[((size_t)(t0 + tl) * 16 + b) * 2048 + j0 + jl] = f2bf(tile[jl][tl]);
    }
}

// ---------------------------------------------------------------------------
// Weight transpose+convert: W [K][N] fp32 -> Bt [N'][K] bf16.
// perm=1 (SRU): within N=2048, n = gate*512+j  ->  n' = j*4+gate
// ---------------------------------------------------------------------------
__global__ __launch_bounds__(256)
void wconv_t(const float* __restrict__ W, ushort* __restrict__ Bt,
             int K, int N, int perm)
{
    __shared__ float tile[64][65];
    const int k0 = blockIdx.x * 64;
    const int n0 = blockIdx.y * 64;
#pragma unroll
    for (int p = 0; p < 16; ++p) {
        int idx = p * 256 + threadIdx.x;
        int kl = idx >> 6, nl = idx & 63;
        tile[kl][nl] = W[(size_t)(k0 + kl) * N + n0 + nl];
    }
    __syncthreads();
#pragma unroll
    for (int p = 0; p < 16; ++p) {
        int idx = p * 256 + threadIdx.x;
        int nl = idx >> 6, kl = idx & 63;
        int n = n0 + nl;
        int row = perm ? ((n & 511) * 4 + (n >> 9)) : n;
        Bt[(size_t)row * K + k0 + kl] = f2bf(tile[kl][nl]);
    }
}

// ---------------------------------------------------------------------------
// LayerNorm over last dim (1024), rows = 8192, fp32 in -> bf16 out.
// ---------------------------------------------------------------------------
__global__ __launch_bounds__(256)
void layernorm1024_bf(const float* __restrict__ x, const float* __restrict__ g,
                      const float* __restrict__ b, ushort* __restrict__ y)
{
    const size_t row = blockIdx.x;
    const float4 v = ((const float4*)(x + row * 1024))[threadIdx.x];
    float s = v.x + v.y + v.z + v.w;
    float s2 = v.x * v.x + v.y * v.y + v.z * v.z + v.w * v.w;
#pragma unroll
    for (int off = 32; off; off >>= 1) {
        s += __shfl_down(s, off);
        s2 += __shfl_down(s2, off);
    }
    __shared__ float red[2][4];
    int wid = threadIdx.x >> 6, lane = threadIdx.x & 63;
    if (lane == 0) { red[0][wid] = s; red[1][wid] = s2; }
    __syncthreads();
    s = red[0][0] + red[0][1] + red[0][2] + red[0][3];
    s2 = red[1][0] + red[1][1] + red[1][2] + red[1][3];
    float mu = s * (1.0f / 1024.0f);
    float var = s2 * (1.0f / 1024.0f) - mu * mu;
    float rstd = rsqrtf(var + 1e-5f);
    float4 gv = ((const float4*)g)[threadIdx.x];
    float4 bv = ((const float4*)b)[threadIdx.x];
    ushort4 o;
    o.x = f2bf((v.x - mu) * rstd * gv.x + bv.x);
    o.y = f2bf((v.y - mu) * rstd * gv.y + bv.y);
    o.z = f2bf((v.z - mu) * rstd * gv.z + bv.z);
    o.w = f2bf((v.w - mu) * rstd * gv.w + bv.w);
    ((ushort4*)(y + row * 1024))[threadIdx.x] = o;
}

// ---------------------------------------------------------------------------
// bf16 MFMA GEMM (m97 recipe): C[M,N] = A[M,K] @ Bt[N,K]^T.
// 128x128 tile, BK=32, 256 thr = 4 waves (2x2), 4x4 16x16x32 frags per wave.
// global_load_lds width-16 staging, linear LDS [128][32].
// ---------------------------------------------------------------------------
template <int OUTBF, int RELU>
__global__ __launch_bounds__(256)
void gemm_bf16(const ushort* __restrict__ A, const ushort* __restrict__ Bt,
               void* __restrict__ C, int M, int N, int K)
{
    __shared__ ushort As[128 * 32];
    __shared__ ushort Bs[128 * 32];
    const int tid = threadIdx.x;
    const int lane = tid & 63, w = tid >> 6;
    const int m0 = blockIdx.y * 128, n0 = blockIdx.x * 128;
    const int srow = lane >> 2;            // staging row within 16-row chunk
    const int skel = (lane & 3) * 8;       // staging k element offset (16 B)
    const int wr = (w >> 1) * 64, wcol = (w & 1) * 64;
    const int fr = lane & 15, fk = (lane >> 4) * 8;

    f32x4 acc[4][4];
#pragma unroll
    for (int m = 0; m < 4; ++m)
#pragma unroll
        for (int n = 0; n < 4; ++n) acc[m][n] = (f32x4){0.f, 0.f, 0.f, 0.f};

    for (int k0 = 0; k0 < K; k0 += 32) {
        __syncthreads();
#pragma unroll
        for (int q = 0; q < 2; ++q) {
            const int ch = w * 2 + q;      // chunk 0..7, 16 rows each
            gload_lds16(A + (size_t)(m0 + ch * 16 + srow) * K + k0 + skel,
                        As + ch * 512);
            gload_lds16(Bt + (size_t)(n0 + ch * 16 + srow) * K + k0 + skel,
                        Bs + ch * 512);
        }
        __syncthreads();
        short8 a[4], b[4];
#pragma unroll
        for (int m = 0; m < 4; ++m)
            a[m] = *(const short8*)&As[(wr + m * 16 + fr) * 32 + fk];
#pragma unroll
        for (int n = 0; n < 4; ++n)
            b[n] = *(const short8*)&Bs[(wcol + n * 16 + fr) * 32 + fk];
#pragma unroll
        for (int m = 0; m < 4; ++m)
#pragma unroll
            for (int n = 0; n < 4; ++n)
                acc[m][n] = __builtin_amdgcn_mfma_f32_16x16x32_bf16(
                    a[m], b[n], acc[m][n], 0, 0, 0);
    }
    // C/D layout: col = lane&15, row = (lane>>4)*4 + reg  [m89-verified]
#pragma unroll
    for (int m = 0; m < 4; ++m) {
#pragma unroll
        for (int r = 0; r < 4; ++r) {
            const int row = m0 + wr + m * 16 + (lane >> 4) * 4 + r;
            const size_t rb = (size_t)row * N;
#pragma unroll
            for (int n = 0; n < 4; ++n) {
                float val = acc[m][n][r];
                if (RELU) val = fmaxf(val, 0.0f);
                const int col = n0 + wcol + n * 16 + fr;
                if (OUTBF) ((ushort*)C)[rb + col] = f2bf(val);
                else       ((float*)C)[rb + col] = val;
            }
        }
    }
}

// ---------------------------------------------------------------------------
// Fused bidirectional SRU scan.
// U bf16 [8192 rows = t*16+b][4096], cols dir*2048 + j*4 + {xt,fp,rp,xp}.
// 16384 threads: gidx>>13 = dir, rest = b*512+j chain. 8-deep reg prefetch.
// ---------------------------------------------------------------------------
__global__ __launch_bounds__(256)
void sru_scan2(const ushort* __restrict__ U, const float* __restrict__ v,
               const float* __restrict__ bb, float* __restrict__ out)
{
    const int gidx = blockIdx.x * 256 + threadIdx.x;
    const int dir = gidx >> 13;
    const int idx = gidx & 8191;
    const int j = idx & 511, b = idx >> 9;
    const float vf = v[dir * 1024 + j],   vr = v[dir * 1024 + 512 + j];
    const float bf_ = bb[dir * 1024 + j], br_ = bb[dir * 1024 + 512 + j];
    const size_t cb = (size_t)dir * 2048 + j * 4;
    const int co = dir * 512 + j;
#define TT(q_) (dir ? (511 - (q_)) : (q_))
    float c = 0.0f;
    uint2 buf[8], nbuf[8];
#pragma unroll
    for (int q = 0; q < 8; ++q)
        buf[q] = *(const uint2*)&U[(size_t)(TT(q) * 16 + b) * 4096 + cb];
    for (int base = 0; base < 512; base += 8) {
        if (base + 8 < 512) {
#pragma unroll
            for (int q = 0; q < 8; ++q)
                nbuf[q] = *(const uint2*)&U[(size_t)(TT(base + 8 + q) * 16 + b) * 4096 + cb];
        } else {
#pragma unroll
            for (int q = 0; q < 8; ++q) nbuf[q] = buf[q];
        }
#pragma unroll
        for (int q = 0; q < 8; ++q) {
            const int t = TT(base + q);
            float xt = b2f(buf[q].x & 0xffffu);
            float fp = b2f(buf[q].x >> 16);
            float rp = b2f(buf[q].y & 0xffffu);
            float xp = b2f(buf[q].y >> 16);
            float f = sigmoidf_(fp + vf * c + bf_);
            float r = sigmoidf_(rp + vr * c + br_);
            c = fmaf(f, c - xt, xt);
            float h = fmaf(r, tanh_fast(c) - xp, xp);
            out[(size_t)(t * 16 + b) * 1024 + co] = h;
        }
#pragma unroll
        for (int q = 0; q < 8; ++q) buf[q] = nbuf[q];
    }
#undef TT
}

// ---------------------------------------------------------------------------
// Final small GEMM (8192,512)@(512,29) with (t,b)->(b,t) output scatter.
// ---------------------------------------------------------------------------
__global__ __launch_bounds__(256)
void cls_out(const float* __restrict__ h1, const float* __restrict__ W2,
             float* __restrict__ out)
{
    const int gidx = blockIdx.x * 256 + threadIdx.x;
    const int n = gidx & 31, m = gidx >> 5;
    if (n >= 29) return;
    const float* hr = h1 + (size_t)m * 512;
    float acc = 0.0f;
    for (int k = 0; k < 512; k += 4) {
        acc = fmaf(hr[k + 0], W2[(k + 0) * 29 + n], acc);
        acc = fmaf(hr[k + 1], W2[(k + 1) * 29 + n], acc);
        acc = fmaf(hr[k + 2], W2[(k + 2) * 29 + n], acc);
        acc = fmaf(hr[k + 3], W2[(k + 3) * 29 + n], acc);
    }
    const int t = m >> 4, b = m & 15;
    out[((size_t)b * 512 + t) * 29 + n] = acc;
}

// ---------------------------------------------------------------------------
// Host orchestration. Workspace (floats, total 50.33M = 201.3 MB):
//   [0,16.8M)        B0: conv buf / U bf16 [8192][4096]
//   [16.8M,25.2M)    B1a: xrow_bf16 / xcB fp32 / h1 fp32
//   [25.2M,33.6M)    B1b: xcA fp32
//   [33.6M,43.25M)   B2a: bf16 weights (proj_bt, sru_bt, w1t)
//   [43.25M,47.45M)  xn_bf16
// Conv phase uses [0,50.33M) as three 16.8M fp32 buffers (before weights).
// ---------------------------------------------------------------------------
extern "C" void kernel_launch(void* const* d_in, const int* in_sizes, int n_in,
                              void* d_out, int out_size, void* d_ws, size_t ws_size,
                              hipStream_t stream)
{
    (void)in_sizes; (void)n_in; (void)out_size; (void)ws_size;
    const float* x      = (const float*)d_in[0];
    const float* cnn_w  = (const float*)d_in[1];
    const float* cnn_b  = (const float*)d_in[2];
    const float* c1w    = (const float*)d_in[3];
    const float* c1b    = (const float*)d_in[4];
    const float* bn1g   = (const float*)d_in[5];
    const float* bn1b   = (const float*)d_in[6];
    const float* bn1m   = (const float*)d_in[7];
    const float* bn1v   = (const float*)d_in[8];
    const float* c2w    = (const float*)d_in[9];
    const float* c2b    = (const float*)d_in[10];
    const float* bn2g   = (const float*)d_in[11];
    const float* bn2b   = (const float*)d_in[12];
    const float* bn2m   = (const float*)d_in[13];
    const float* bn2v   = (const float*)d_in[14];
    const float* projW  = (const float*)d_in[15];
    const float* sruW   = (const float*)d_in[16];
    const float* sruV   = (const float*)d_in[17];
    const float* sruB   = (const float*)d_in[18];
    const float* sruLNg = (const float*)d_in[19];
    const float* sruLNb = (const float*)d_in[20];
    const float* clsLNg = (const float*)d_in[21];
    const float* clsLNb = (const float*)d_in[22];
    const float* W1     = (const float*)d_in[23];
    const float* W2     = (const float*)d_in[24];
    float* out = (float*)d_out;
    float* ws  = (float*)d_ws;

    float* B0 = ws;
    float* B1 = ws + 16777216;
    float* B2 = ws + 33554432;

    ushort* Ubuf    = (ushort*)ws;                  // [8192][4096] bf16
    ushort* xrow_bf = (ushort*)(ws + 16777216);     // [8192][2048] bf16
    float*  xcB     = ws + 16777216;                // fp32 [8192][1024]
    float*  xcA     = ws + 25165824;                // fp32 [8192][1024]
    ushort* proj_bt = (ushort*)(ws + 33554432);     // [1024][2048]
    ushort* sru_bt  = proj_bt + 2097152;            // 8 x [2048][1024]
    ushort* w1t     = sru_bt + 16777216;            // [512][1024]
    ushort* xn_bf   = (ushort*)(ws + 43253760);     // [8192][1024] bf16

    dim3 blk(256);

    // --- conv phase (fp32, unchanged) ---
    conv_stem<<<dim3(8, 16, 16), blk, 0, stream>>>(x, cnn_w, cnn_b, B0);
    float* ybuf = B0; float* tbuf = B1; float* obuf = B2;
    for (int i = 0; i < 3; ++i) {
        conv3x3_bn<false><<<dim3(8, 16, 16), blk, 0, stream>>>(
            ybuf, c1w + i * 9216, c1b + i * 32, bn1g + i * 32, bn1b + i * 32,
            bn1m + i * 32, bn1v + i * 32, nullptr, tbuf);
        conv3x3_bn<true><<<dim3(8, 16, 16), blk, 0, stream>>>(
            tbuf, c2w + i * 9216, c2b + i * 32, bn2g + i * 32, bn2b + i * 32,
            bn2m + i * 32, bn2v + i * 32, ybuf, obuf);
        float* ny = obuf; obuf = tbuf; tbuf = ybuf; ybuf = ny;
    }
    // ybuf == B0 holds conv output; B1/B2 free.

    // --- gather to bf16 rows ---
    gather_xrow<<<dim3(8, 32, 16), blk, 0, stream>>>(ybuf, xrow_bf);

    // --- weight conversion (after convs free B2) ---
    wconv_t<<<dim3(32, 16), blk, 0, stream>>>(projW, proj_bt, 2048, 1024, 0);
    for (int s = 0; s < 8; ++s)
        wconv_t<<<dim3(16, 32), blk, 0, stream>>>(
            sruW + (size_t)s * 2097152, sru_bt + (size_t)s * 2097152, 1024, 2048, 1);
    wconv_t<<<dim3(16, 8), blk, 0, stream>>>(W1, w1t, 1024, 512, 0);

    // --- proj GEMM: (8192,2048)@(2048,1024) -> xcA fp32 ---
    gemm_bf16<0, 0><<<dim3(8, 64), blk, 0, stream>>>(
        xrow_bf, proj_bt, xcA, 8192, 1024, 2048);

    // --- SRU layers ---
    float* xc = xcA; float* xnx = xcB;
    for (int l = 0; l < 4; ++l) {
        layernorm1024_bf<<<8192, blk, 0, stream>>>(
            xc, sruLNg + l * 1024, sruLNb + l * 1024, xn_bf);
        // both directions in one GEMM: Bt = [4096][1024], C = U [8192][4096] bf16
        gemm_bf16<1, 0><<<dim3(32, 64), blk, 0, stream>>>(
            xn_bf, sru_bt + (size_t)l * 4194304, Ubuf, 8192, 4096, 1024);
        sru_scan2<<<64, blk, 0, stream>>>(
            Ubuf, sruV + l * 2048, sruB + l * 2048, xnx);
        float* tmp = xc; xc = xnx; xnx = tmp;
    }
    // 4 layers -> xc == xcA, xnx == xcB free.

    // --- classifier ---
    layernorm1024_bf<<<8192, blk, 0, stream>>>(xc, clsLNg, clsLNb, xn_bf);
    float* h1 = xcB;   // [8192][512] fp32
    gemm_bf16<0, 1><<<dim3(4, 64), blk, 0, stream>>>(
        xn_bf, w1t, h1, 8192, 512, 1024);
    cls_out<<<1024, blk, 0, stream>>>(h1, W2, out);
}

// Round 4
// 1310.673 us; speedup vs baseline: 6.0185x; 2.4803x over previous
//
#include <hip/hip_runtime.h>
#include <cstddef>

#define DEVFN __device__ __forceinline__

typedef __attribute__((ext_vector_type(8))) short short8;          // 8 bf16
typedef __attribute__((ext_vector_type(8))) unsigned short ushort8;
typedef __attribute__((ext_vector_type(4))) float f32x4;           // MFMA acc

DEVFN float sigmoidf_(float x) { return 1.0f / (1.0f + __expf(-x)); }
DEVFN float tanh_fast(float x) {
    float e = __expf(2.0f * x);
    return 1.0f - 2.0f / (e + 1.0f);
}
DEVFN unsigned short f2bf(float f) {            // round-to-nearest-even
    unsigned int u = __float_as_uint(f);
    return (unsigned short)((u + 0x7FFFu + ((u >> 16) & 1u)) >> 16);
}
DEVFN float b2f(unsigned int bits) { return __uint_as_float(bits << 16); }

DEVFN void gload_lds16(const ushort* g, ushort* l) {
    __builtin_amdgcn_global_load_lds(
        (const __attribute__((address_space(1))) unsigned int*)g,
        (__attribute__((address_space(3))) unsigned int*)l, 16, 0, 0);
}

// Padded NHWC geometry: [16 b][66 hs][514 ws][32 c], hs = h+1, ws = w+1.
#define PADN 17371008u

// ---------------------------------------------------------------------------
// Zero the padding ring of the 4 padded NHWC tensors (uint granularity).
// ---------------------------------------------------------------------------
__global__ __launch_bounds__(256)
void ring_zero(ushort* A, ushort* B, ushort* C, ushort* D)
{
    int idx = blockIdx.x * 256 + threadIdx.x;
    if (idx >= 296960) return;
    size_t uoff;
    if (idx < 263168) {                       // rows hs in {0,65}
        int b = idx / 16448, r = idx % 16448;
        int hs = (r < 8224) ? 0 : 65;
        int o = (r < 8224) ? r : r - 8224;
        uoff = (((size_t)(b * 66 + hs) * 514) * 32 + (size_t)o * 2) >> 1;
    } else {                                  // cols ws in {0,513}
        int j = idx - 263168;
        int b = j / 2112, r = j % 2112;
        int hs = r >> 5, e = r & 31;
        int wsp = (e < 16) ? 0 : 513;
        int c2 = e & 15;
        uoff = (((size_t)(b * 66 + hs) * 514 + wsp) * 32 + (size_t)c2 * 2) >> 1;
    }
    ((uint*)A)[uoff] = 0; ((uint*)B)[uoff] = 0;
    ((uint*)C)[uoff] = 0; ((uint*)D)[uoff] = 0;
}

// ---------------------------------------------------------------------------
// Conv-weight prep: [co][ci][3][3] fp32 -> [lay][q][co][ci] bf16 hi/lo.
// lay = 2*i (c1w[i]) or 2*i+1 (c2w[i]).
// ---------------------------------------------------------------------------
__global__ __launch_bounds__(256)
void conv_wprep(const float* __restrict__ c1w, const float* __restrict__ c2w,
                ushort* __restrict__ whi, ushort* __restrict__ wlo)
{
    const int lay = blockIdx.x;               // 0..5
    const int i = lay >> 1;
    const float* src = (lay & 1) ? (c2w + i * 9216) : (c1w + i * 9216);
    for (int e = threadIdx.x; e < 9216; e += 256) {
        int co = e / 288, rem = e % 288, ci = rem / 9, q = rem % 9;
        float v = src[e];
        unsigned short hi = f2bf(v);
        unsigned short lo = f2bf(v - b2f(hi));
        int dst = ((lay * 9 + q) * 32 + co) * 32 + ci;
        whi[dst] = hi; wlo[dst] = lo;
    }
}

// ---------------------------------------------------------------------------
// Conv stem -> padded NHWC hi/lo. x (16,1,128,1024), stride 2, pad 1.
// ---------------------------------------------------------------------------
__global__ __launch_bounds__(256)
void conv_stem_p(const float* __restrict__ x, const float* __restrict__ w,
                 const float* __restrict__ cb,
                 ushort* __restrict__ Xhi, ushort* __restrict__ Xlo)
{
    const int b = blockIdx.z;
    const int h = blockIdx.y * 4 + (threadIdx.x >> 6);
    const int wc = blockIdx.x * 64 + (threadIdx.x & 63);
    float iv[9];
#pragma unroll
    for (int kh = 0; kh < 3; ++kh)
#pragma unroll
        for (int kw = 0; kw < 3; ++kw) {
            int ih = 2 * h - 1 + kh, iw = 2 * wc - 1 + kw;
            iv[kh * 3 + kw] = (ih >= 0 && ih < 128 && iw >= 0 && iw < 1024)
                ? x[(size_t)b * 131072 + (size_t)ih * 1024 + iw] : 0.0f;
        }
    unsigned short hi[32], lo[32];
#pragma unroll
    for (int co = 0; co < 32; ++co) {
        const float* wp = w + co * 9;
        float a = cb[co];
#pragma unroll
        for (int q = 0; q < 9; ++q) a = fmaf(iv[q], wp[q], a);
        hi[co] = f2bf(a);
        lo[co] = f2bf(a - b2f(hi[co]));
    }
    const size_t o = ((size_t)(b * 66 + h + 1) * 514 + wc + 1) * 32;
#pragma unroll
    for (int v = 0; v < 4; ++v) {
        ushort8 uh, ul;
#pragma unroll
        for (int e = 0; e < 8; ++e) { uh[e] = hi[v * 8 + e]; ul[e] = lo[v * 8 + e]; }
        *(ushort8*)(Xhi + o + v * 8) = uh;
        *(ushort8*)(Xlo + o + v * 8) = ul;
    }
}

// ---------------------------------------------------------------------------
// MFMA implicit-GEMM conv 3x3 (32->32) + BN (+res) + ReLU, bf16x3 split.
// Grid (4 wtiles, 64 h, 16 b), 256 thr. M-tile = 128 w, N = 32 co, K = 9x32.
// Per k-step q=(kh,kw): A-slice = contiguous 128x32 NHWC chunk -> gload_lds.
// ---------------------------------------------------------------------------
template <int RES>
__global__ __launch_bounds__(256)
void conv_mfma(const ushort* __restrict__ Phi, const ushort* __restrict__ Plo,
               const ushort* __restrict__ gwhi, const ushort* __restrict__ gwlo,
               const float* __restrict__ g, const float* __restrict__ bbn,
               const float* __restrict__ mn, const float* __restrict__ vn,
               const float* __restrict__ cbv,
               const ushort* __restrict__ Rhi, const ushort* __restrict__ Rlo,
               ushort* __restrict__ Ohi, ushort* __restrict__ Olo)
{
    __shared__ __align__(16) ushort Ash[4096], Asl[4096];
    __shared__ __align__(16) ushort Wsh[9216], Wsl[9216];
    const int tid = threadIdx.x, lane = tid & 63, wv = tid >> 6;
    const int b = blockIdx.z, h = blockIdx.y, w0 = blockIdx.x * 128;

    for (int i = tid; i < 1152; i += 256) {      // stage 9 q-tiles of weights
        ((uint4*)Wsh)[i] = ((const uint4*)gwhi)[i];
        ((uint4*)Wsl)[i] = ((const uint4*)gwlo)[i];
    }
    const int srow = lane >> 2, skel = (lane & 3) * 8;
    const int wr = wv * 32;                      // wave's 32 m-positions
    const int fr = lane & 15, fk = (lane >> 4) * 8;

    f32x4 acc[2][2];
#pragma unroll
    for (int m = 0; m < 2; ++m)
#pragma unroll
        for (int n = 0; n < 2; ++n) acc[m][n] = (f32x4){0.f, 0.f, 0.f, 0.f};

#pragma unroll
    for (int kh = 0; kh < 3; ++kh)
#pragma unroll
    for (int kw = 0; kw < 3; ++kw) {
        const int q = kh * 3 + kw;
        const size_t base = ((size_t)(b * 66 + h + kh) * 514 + w0 + kw) * 32;
        __syncthreads();
#pragma unroll
        for (int qq = 0; qq < 2; ++qq) {
            const int ch = wv * 2 + qq;          // chunk: 16 rows x 64 B
            gload_lds16(Phi + base + (ch * 16 + srow) * 32 + skel, Ash + ch * 512);
            gload_lds16(Plo + base + (ch * 16 + srow) * 32 + skel, Asl + ch * 512);
        }
        __syncthreads();
        short8 ah[2], al[2], bh[2], bl[2];
#pragma unroll
        for (int m = 0; m < 2; ++m) {
            ah[m] = *(const short8*)&Ash[(wr + m * 16 + fr) * 32 + fk];
            al[m] = *(const short8*)&Asl[(wr + m * 16 + fr) * 32 + fk];
        }
#pragma unroll
        for (int n = 0; n < 2; ++n) {
            bh[n] = *(const short8*)&Wsh[q * 1024 + (n * 16 + fr) * 32 + fk];
            bl[n] = *(const short8*)&Wsl[q * 1024 + (n * 16 + fr) * 32 + fk];
        }
#pragma unroll
        for (int m = 0; m < 2; ++m)
#pragma unroll
            for (int n = 0; n < 2; ++n) {
                acc[m][n] = __builtin_amdgcn_mfma_f32_16x16x32_bf16(ah[m], bh[n], acc[m][n], 0, 0, 0);
                acc[m][n] = __builtin_amdgcn_mfma_f32_16x16x32_bf16(al[m], bh[n], acc[m][n], 0, 0, 0);
                acc[m][n] = __builtin_amdgcn_mfma_f32_16x16x32_bf16(ah[m], bl[n], acc[m][n], 0, 0, 0);
            }
    }
    // epilogue: BN fold (+conv bias) (+res) + ReLU, split to hi/lo, write NHWC
    float sc[2], sh[2];
#pragma unroll
    for (int n = 0; n < 2; ++n) {
        const int co = n * 16 + fr;
        sc[n] = g[co] * rsqrtf(vn[co] + 1e-5f);
        sh[n] = bbn[co] - mn[co] * sc[n] + cbv[co] * sc[n];
    }
#pragma unroll
    for (int m = 0; m < 2; ++m)
#pragma unroll
        for (int r = 0; r < 4; ++r) {
            const int wl = wr + m * 16 + (lane >> 4) * 4 + r;
            const size_t oidx = ((size_t)(b * 66 + h + 1) * 514 + w0 + wl + 1) * 32;
#pragma unroll
            for (int n = 0; n < 2; ++n) {
                const int co = n * 16 + fr;
                float val = acc[m][n][r] * sc[n] + sh[n];
                if (RES) val += b2f(Rhi[oidx + co]) + b2f(Rlo[oidx + co]);
                val = fmaxf(val, 0.0f);
                unsigned short hi = f2bf(val);
                Ohi[oidx + co] = hi;
                Olo[oidx + co] = f2bf(val - b2f(hi));
            }
        }
}

// ---------------------------------------------------------------------------
// Gather: padded NHWC hi -> xrow_bf[(w*16+b)][c*64+h]  (8192 x 2048 bf16)
// ---------------------------------------------------------------------------
__global__ __launch_bounds__(256)
void gather_pad(const ushort* __restrict__ Xhi, ushort* __restrict__ xrow)
{
    __shared__ ushort tile[64 * 16 * 32];        // [h][wl][c], 64 KB
    const int b = blockIdx.y, w0 = blockIdx.x * 16;
    for (int k = threadIdx.x; k < 4096; k += 256) {
        int h = k >> 6, rem = k & 63, wl = rem >> 2, c8 = (rem & 3) * 8;
        const ushort* src = Xhi + ((size_t)(b * 66 + h + 1) * 514 + w0 + 1 + wl) * 32 + c8;
        *(ushort8*)&tile[(h * 16 + wl) * 32 + c8] = *(const ushort8*)src;
    }
    __syncthreads();
    for (int k = threadIdx.x; k < 4096; k += 256) {
        int wl = k >> 8, rem = k & 255, c = rem >> 3, h8 = (rem & 7) * 8;
        ushort8 v;
#pragma unroll
        for (int e = 0; e < 8; ++e) v[e] = tile[((h8 + e) * 16 + wl) * 32 + c];
        *(ushort8*)&xrow[((size_t)(w0 + wl) * 16 + b) * 2048 + c * 64 + h8] = v;
    }
}

// ---------------------------------------------------------------------------
// Weight transpose+convert: W [K][N] fp32 -> Bt [N'][K] bf16.
// perm=1 (SRU): within N=2048, n = gate*512+j  ->  n' = j*4+gate
// ---------------------------------------------------------------------------
__global__ __launch_bounds__(256)
void wconv_t(const float* __restrict__ W, ushort* __restrict__ Bt,
             int K, int N, int perm)
{
    __shared__ float tile[64][65];
    const int k0 = blockIdx.x * 64;
    const int n0 = blockIdx.y * 64;
#pragma unroll
    for (int p = 0; p < 16; ++p) {
        int idx = p * 256 + threadIdx.x;
        int kl = idx >> 6, nl = idx & 63;
        tile[kl][nl] = W[(size_t)(k0 + kl) * N + n0 + nl];
    }
    __syncthreads();
#pragma unroll
    for (int p = 0; p < 16; ++p) {
        int idx = p * 256 + threadIdx.x;
        int nl = idx >> 6, kl = idx & 63;
        int n = n0 + nl;
        int row = perm ? ((n & 511) * 4 + (n >> 9)) : n;
        Bt[(size_t)row * K + k0 + kl] = f2bf(tile[kl][nl]);
    }
}

// ---------------------------------------------------------------------------
// LayerNorm over last dim (1024), rows = 8192, fp32 in -> bf16 out.
// ---------------------------------------------------------------------------
__global__ __launch_bounds__(256)
void layernorm1024_bf(const float* __restrict__ x, const float* __restrict__ g,
                      const float* __restrict__ b, ushort* __restrict__ y)
{
    const size_t row = blockIdx.x;
    const float4 v = ((const float4*)(x + row * 1024))[threadIdx.x];
    float s = v.x + v.y + v.z + v.w;
    float s2 = v.x * v.x + v.y * v.y + v.z * v.z + v.w * v.w;
#pragma unroll
    for (int off = 32; off; off >>= 1) {
        s += __shfl_down(s, off);
        s2 += __shfl_down(s2, off);
    }
    __shared__ float red[2][4];
    int wid = threadIdx.x >> 6, lane = threadIdx.x & 63;
    if (lane == 0) { red[0][wid] = s; red[1][wid] = s2; }
    __syncthreads();
    s = red[0][0] + red[0][1] + red[0][2] + red[0][3];
    s2 = red[1][0] + red[1][1] + red[1][2] + red[1][3];
    float mu = s * (1.0f / 1024.0f);
    float var = s2 * (1.0f / 1024.0f) - mu * mu;
    float rstd = rsqrtf(var + 1e-5f);
    float4 gv = ((const float4*)g)[threadIdx.x];
    float4 bv = ((const float4*)b)[threadIdx.x];
    ushort4 o;
    o.x = f2bf((v.x - mu) * rstd * gv.x + bv.x);
    o.y = f2bf((v.y - mu) * rstd * gv.y + bv.y);
    o.z = f2bf((v.z - mu) * rstd * gv.z + bv.z);
    o.w = f2bf((v.w - mu) * rstd * gv.w + bv.w);
    ((ushort4*)(y + row * 1024))[threadIdx.x] = o;
}

// ---------------------------------------------------------------------------
// bf16 MFMA GEMM (m97 recipe): C[M,N] = A[M,K] @ Bt[N,K]^T.
// ---------------------------------------------------------------------------
template <int OUTBF, int RELU>
__global__ __launch_bounds__(256)
void gemm_bf16(const ushort* __restrict__ A, const ushort* __restrict__ Bt,
               void* __restrict__ C, int M, int N, int K)
{
    __shared__ __align__(16) ushort As[128 * 32];
    __shared__ __align__(16) ushort Bs[128 * 32];
    const int tid = threadIdx.x;
    const int lane = tid & 63, w = tid >> 6;
    const int m0 = blockIdx.y * 128, n0 = blockIdx.x * 128;
    const int srow = lane >> 2;
    const int skel = (lane & 3) * 8;
    const int wr = (w >> 1) * 64, wcol = (w & 1) * 64;
    const int fr = lane & 15, fk = (lane >> 4) * 8;

    f32x4 acc[4][4];
#pragma unroll
    for (int m = 0; m < 4; ++m)
#pragma unroll
        for (int n = 0; n < 4; ++n) acc[m][n] = (f32x4){0.f, 0.f, 0.f, 0.f};

    for (int k0 = 0; k0 < K; k0 += 32) {
        __syncthreads();
#pragma unroll
        for (int q = 0; q < 2; ++q) {
            const int ch = w * 2 + q;
            gload_lds16(A + (size_t)(m0 + ch * 16 + srow) * K + k0 + skel,
                        As + ch * 512);
            gload_lds16(Bt + (size_t)(n0 + ch * 16 + srow) * K + k0 + skel,
                        Bs + ch * 512);
        }
        __syncthreads();
        short8 a[4], b[4];
#pragma unroll
        for (int m = 0; m < 4; ++m)
            a[m] = *(const short8*)&As[(wr + m * 16 + fr) * 32 + fk];
#pragma unroll
        for (int n = 0; n < 4; ++n)
            b[n] = *(const short8*)&Bs[(wcol + n * 16 + fr) * 32 + fk];
#pragma unroll
        for (int m = 0; m < 4; ++m)
#pragma unroll
            for (int n = 0; n < 4; ++n)
                acc[m][n] = __builtin_amdgcn_mfma_f32_16x16x32_bf16(
                    a[m], b[n], acc[m][n], 0, 0, 0);
    }
#pragma unroll
    for (int m = 0; m < 4; ++m) {
#pragma unroll
        for (int r = 0; r < 4; ++r) {
            const int row = m0 + wr + m * 16 + (lane >> 4) * 4 + r;
            const size_t rb = (size_t)row * N;
#pragma unroll
            for (int n = 0; n < 4; ++n) {
                float val = acc[m][n][r];
                if (RELU) val = fmaxf(val, 0.0f);
                const int col = n0 + wcol + n * 16 + fr;
                if (OUTBF) ((ushort*)C)[rb + col] = f2bf(val);
                else       ((float*)C)[rb + col] = val;
            }
        }
    }
}

// ---------------------------------------------------------------------------
// Fused bidirectional SRU scan (U bf16, gate-interleaved cols).
// ---------------------------------------------------------------------------
__global__ __launch_bounds__(256)
void sru_scan2(const ushort* __restrict__ U, const float* __restrict__ v,
               const float* __restrict__ bb, float* __restrict__ out)
{
    const int gidx = blockIdx.x * 256 + threadIdx.x;
    const int dir = gidx >> 13;
    const int idx = gidx & 8191;
    const int j = idx & 511, b = idx >> 9;
    const float vf = v[dir * 1024 + j],   vr = v[dir * 1024 + 512 + j];
    const float bf_ = bb[dir * 1024 + j], br_ = bb[dir * 1024 + 512 + j];
    const size_t cb = (size_t)dir * 2048 + j * 4;
    const int co = dir * 512 + j;
#define TT(q_) (dir ? (511 - (q_)) : (q_))
    float c = 0.0f;
    uint2 buf[8], nbuf[8];
#pragma unroll
    for (int q = 0; q < 8; ++q)
        buf[q] = *(const uint2*)&U[(size_t)(TT(q) * 16 + b) * 4096 + cb];
    for (int base = 0; base < 512; base += 8) {
        if (base + 8 < 512) {
#pragma unroll
            for (int q = 0; q < 8; ++q)
                nbuf[q] = *(const uint2*)&U[(size_t)(TT(base + 8 + q) * 16 + b) * 4096 + cb];
        } else {
#pragma unroll
            for (int q = 0; q < 8; ++q) nbuf[q] = buf[q];
        }
#pragma unroll
        for (int q = 0; q < 8; ++q) {
            const int t = TT(base + q);
            float xt = b2f(buf[q].x & 0xffffu);
            float fp = b2f(buf[q].x >> 16);
            float rp = b2f(buf[q].y & 0xffffu);
            float xp = b2f(buf[q].y >> 16);
            float f = sigmoidf_(fp + vf * c + bf_);
            float r = sigmoidf_(rp + vr * c + br_);
            c = fmaf(f, c - xt, xt);
            float h = fmaf(r, tanh_fast(c) - xp, xp);
            out[(size_t)(t * 16 + b) * 1024 + co] = h;
        }
#pragma unroll
        for (int q = 0; q < 8; ++q) buf[q] = nbuf[q];
    }
#undef TT
}

// ---------------------------------------------------------------------------
// Final small GEMM (8192,512)@(512,29) with (t,b)->(b,t) output scatter.
// ---------------------------------------------------------------------------
__global__ __launch_bounds__(256)
void cls_out(const float* __restrict__ h1, const float* __restrict__ W2,
             float* __restrict__ out)
{
    const int gidx = blockIdx.x * 256 + threadIdx.x;
    const int n = gidx & 31, m = gidx >> 5;
    if (n >= 29) return;
    const float* hr = h1 + (size_t)m * 512;
    float acc = 0.0f;
    for (int k = 0; k < 512; k += 4) {
        acc = fmaf(hr[k + 0], W2[(k + 0) * 29 + n], acc);
        acc = fmaf(hr[k + 1], W2[(k + 1) * 29 + n], acc);
        acc = fmaf(hr[k + 2], W2[(k + 2) * 29 + n], acc);
        acc = fmaf(hr[k + 3], W2[(k + 3) * 29 + n], acc);
    }
    const int t = m >> 4, b = m & 15;
    out[((size_t)b * 512 + t) * 29 + n] = acc;
}

// ---------------------------------------------------------------------------
// Host orchestration. Workspace (float idx, peak 47,448,064 f = 189.8 MB):
// conv:  Xhi[0) Xlo[8685504) Thi[17371008) Tlo[26056512)  (ushort PADN each)
//        convw hi/lo @34742016f ; xrow @34865152f ; xn_bf @43253760f
// post:  Ubuf[0) xch@16777216 proj_bt@25165824 sru_bt@26214400 w1t@34603008
//        h1 -> reuse [0, 4.2M) after scans.
// ---------------------------------------------------------------------------
extern "C" void kernel_launch(void* const* d_in, const int* in_sizes, int n_in,
                              void* d_out, int out_size, void* d_ws, size_t ws_size,
                              hipStream_t stream)
{
    (void)in_sizes; (void)n_in; (void)out_size; (void)ws_size;
    const float* x      = (const float*)d_in[0];
    const float* cnn_w  = (const float*)d_in[1];
    const float* cnn_b  = (const float*)d_in[2];
    const float* c1w    = (const float*)d_in[3];
    const float* c1b    = (const float*)d_in[4];
    const float* bn1g   = (const float*)d_in[5];
    const float* bn1b   = (const float*)d_in[6];
    const float* bn1m   = (const float*)d_in[7];
    const float* bn1v   = (const float*)d_in[8];
    const float* c2w    = (const float*)d_in[9];
    const float* c2b    = (const float*)d_in[10];
    const float* bn2g   = (const float*)d_in[11];
    const float* bn2b   = (const float*)d_in[12];
    const float* bn2m   = (const float*)d_in[13];
    const float* bn2v   = (const float*)d_in[14];
    const float* projW  = (const float*)d_in[15];
    const float* sruW   = (const float*)d_in[16];
    const float* sruV   = (const float*)d_in[17];
    const float* sruB   = (const float*)d_in[18];
    const float* sruLNg = (const float*)d_in[19];
    const float* sruLNb = (const float*)d_in[20];
    const float* clsLNg = (const float*)d_in[21];
    const float* clsLNb = (const float*)d_in[22];
    const float* W1     = (const float*)d_in[23];
    const float* W2     = (const float*)d_in[24];
    float* out = (float*)d_out;
    float* ws  = (float*)d_ws;

    ushort* Xhi = (ushort*)ws;
    ushort* Xlo = Xhi + PADN;
    ushort* Thi = Xlo + PADN;
    ushort* Tlo = Thi + PADN;
    ushort* convw_hi = (ushort*)(ws + 34742016);
    ushort* convw_lo = convw_hi + 55296;
    ushort* xrow_bf  = (ushort*)(ws + 34865152);   // [8192][2048]
    ushort* xn_bf    = (ushort*)(ws + 43253760);   // [8192][1024]
    ushort* Ubuf     = (ushort*)ws;                // [8192][4096]
    float*  xch      = ws + 16777216;              // [8192][1024] fp32
    ushort* proj_bt  = (ushort*)(ws + 25165824);   // [1024][2048]
    ushort* sru_bt   = (ushort*)(ws + 26214400);   // 8 x [2048][1024]
    ushort* w1t      = (ushort*)(ws + 34603008);   // [512][1024]
    float*  h1       = ws;                         // [8192][512] fp32

    dim3 blk(256);

    // --- conv phase ---
    ring_zero<<<1160, blk, 0, stream>>>(Xhi, Xlo, Thi, Tlo);
    conv_wprep<<<6, blk, 0, stream>>>(c1w, c2w, convw_hi, convw_lo);
    conv_stem_p<<<dim3(8, 16, 16), blk, 0, stream>>>(x, cnn_w, cnn_b, Xhi, Xlo);
    for (int i = 0; i < 3; ++i) {
        const int l1 = 2 * i, l2 = 2 * i + 1;
        conv_mfma<0><<<dim3(4, 64, 16), blk, 0, stream>>>(
            Xhi, Xlo, convw_hi + l1 * 9216, convw_lo + l1 * 9216,
            bn1g + i * 32, bn1b + i * 32, bn1m + i * 32, bn1v + i * 32,
            c1b + i * 32, nullptr, nullptr, Thi, Tlo);
        conv_mfma<1><<<dim3(4, 64, 16), blk, 0, stream>>>(
            Thi, Tlo, convw_hi + l2 * 9216, convw_lo + l2 * 9216,
            bn2g + i * 32, bn2b + i * 32, bn2m + i * 32, bn2v + i * 32,
            c2b + i * 32, Xhi, Xlo, Xhi, Xlo);
    }

    // --- GEMM weight conversion (conv T-buffers dead now) ---
    wconv_t<<<dim3(32, 16), blk, 0, stream>>>(projW, proj_bt, 2048, 1024, 0);
    for (int s = 0; s < 8; ++s)
        wconv_t<<<dim3(16, 32), blk, 0, stream>>>(
            sruW + (size_t)s * 2097152, sru_bt + (size_t)s * 2097152, 1024, 2048, 1);
    wconv_t<<<dim3(16, 8), blk, 0, stream>>>(W1, w1t, 1024, 512, 0);

    // --- gather to bf16 rows ---
    gather_pad<<<dim3(32, 16), blk, 0, stream>>>(Xhi, xrow_bf);

    // --- proj GEMM: (8192,2048)@(2048,1024) -> xch fp32 ---
    gemm_bf16<0, 0><<<dim3(8, 64), blk, 0, stream>>>(
        xrow_bf, proj_bt, xch, 8192, 1024, 2048);

    // --- SRU layers (in-place h ping: LN(xch)->xn_bf, GEMM->U, scan->xch) ---
    for (int l = 0; l < 4; ++l) {
        layernorm1024_bf<<<8192, blk, 0, stream>>>(
            xch, sruLNg + l * 1024, sruLNb + l * 1024, xn_bf);
        gemm_bf16<1, 0><<<dim3(32, 64), blk, 0, stream>>>(
            xn_bf, sru_bt + (size_t)l * 4194304, Ubuf, 8192, 4096, 1024);
        sru_scan2<<<64, blk, 0, stream>>>(
            Ubuf, sruV + l * 2048, sruB + l * 2048, xch);
    }

    // --- classifier ---
    layernorm1024_bf<<<8192, blk, 0, stream>>>(xch, clsLNg, clsLNb, xn_bf);
    gemm_bf16<0, 1><<<dim3(4, 64), blk, 0, stream>>>(
        xn_bf, w1t, h1, 8192, 512, 1024);
    cls_out<<<1024, blk, 0, stream>>>(h1, W2, out);
}